// Round 6
// baseline (272.221 us; speedup 1.0000x reference)
//
#include <hip/hip_runtime.h>
#include <hip/hip_bf16.h>

#define NEG_SLOPE 0.2f

typedef __attribute__((ext_vector_type(8))) short bf16x8;
typedef __attribute__((ext_vector_type(4))) float f32x4;

__device__ __forceinline__ float lrelu(float v) { return v > 0.0f ? v : NEG_SLOPE * v; }

__device__ __forceinline__ unsigned bf16pair(float a, float b) {
    unsigned ua = __float_as_uint(a), ub = __float_as_uint(b);
    ua = (ua + 0x7FFFu + ((ua >> 16) & 1u)) >> 16;
    ub = (ub + 0x7FFFu + ((ub >> 16) & 1u)) >> 16;
    return ua | (ub << 16);
}

// async global->LDS, 16B per lane; LDS dest is wave-uniform base + lane*16
__device__ __forceinline__ void gload16(const void* g, void* l) {
    __builtin_amdgcn_global_load_lds(
        (const __attribute__((address_space(1))) unsigned*)g,
        (__attribute__((address_space(3))) unsigned*)l, 16, 0, 0);
}

// ---------------- prep: x->xb bf16, W->Wt bf16 transposed, deg histogram ----
__global__ __launch_bounds__(256) void k_prep(const float* __restrict__ x,
                                              const float* __restrict__ W,
                                              const int* __restrict__ ei,
                                              unsigned* __restrict__ deg,
                                              unsigned* __restrict__ xb,
                                              unsigned short* __restrict__ Wt,
                                              int N, int E) {
    int gid = blockIdx.x * 256 + threadIdx.x;
    int gsz = gridDim.x * 256;
    // x (fp32) -> xb (bf16 pairs), same linear order
    int nf4 = N * 32;
    for (int i = gid; i < nf4; i += gsz) {
        float4 f = ((const float4*)x)[i];
        uint2 u;
        u.x = bf16pair(f.x, f.y);
        u.y = bf16pair(f.z, f.w);
        ((uint2*)xb)[i] = u;
    }
    // W fp32 [k][n] -> Wt bf16 [n][k]
    if (gid < 16384) {
        int col = gid >> 7, k = gid & 127;
        float v = W[(size_t)k * 128 + col];
        unsigned u = __float_as_uint(v);
        u = (u + 0x7FFFu + ((u >> 16) & 1u)) >> 16;
        Wt[col * 128 + k] = (unsigned short)u;
    }
    // degree histogram over dst
    for (int i = gid; i < E; i += gsz)
        atomicAdd(&deg[ei[(size_t)E + i]], 1u);
}

// ---------------- MFMA GEMM: h = xb @ Wt^T, fused att logits ----------------
// 512 threads (8 waves), 128 rows x 128 cols, K=128. A/B staged with
// global_load_lds (linear LDS, inverse-swizzled global source).
__global__ __launch_bounds__(512, 4) void k_gemm(const unsigned* __restrict__ xb,
                                                 const unsigned short* __restrict__ Wt,
                                                 const float* __restrict__ att_src,
                                                 const float* __restrict__ att_dst,
                                                 unsigned* __restrict__ hb,
                                                 float* __restrict__ a_src,
                                                 float* __restrict__ a_dst, int N) {
    __shared__ unsigned char smA[32768];  // [128 r][16 chunks] 16B-chunks, chunk c holds global c^(r&7)
    __shared__ unsigned char smB[32768];  // [128 col][16 chunks], same swizzle
    int t = threadIdx.x;
    int w = t >> 6, lane = t & 63;
    int row0 = blockIdx.x * 128;

    // stage A + B: 4 + 4 global_load_lds per thread
#pragma unroll
    for (int it = 0; it < 4; ++it) {
        int L = w * 256 + it * 64 + lane;   // chunk index 0..2047
        int r = L >> 4, c = L & 15;
        int cg = c ^ (r & 7);
        int gr = row0 + r;
        if (gr >= N) gr = N - 1;
        gload16(xb + (size_t)gr * 64 + cg * 4, smA + (size_t)w * 4096 + it * 1024);
        gload16((const unsigned*)Wt + r * 64 + cg * 4, smB + (size_t)w * 4096 + it * 1024);
    }
    __syncthreads();

    int lr = lane & 15, lg = lane >> 4;
    int ar = w * 16 + lr;

    f32x4 acc[8];
#pragma unroll
    for (int j = 0; j < 8; ++j)
#pragma unroll
        for (int q = 0; q < 4; ++q) acc[j][q] = 0.f;

#pragma unroll
    for (int kc = 0; kc < 4; ++kc) {
        bf16x8 av = *(const bf16x8*)&smA[ar * 256 + (((kc * 4 + lg) ^ (ar & 7)) * 16)];
        bf16x8 bv[8];
#pragma unroll
        for (int cf = 0; cf < 8; ++cf) {
            int bc = cf * 16 + lr;
            bv[cf] = *(const bf16x8*)&smB[bc * 256 + (((kc * 4 + lg) ^ (bc & 7)) * 16)];
        }
#pragma unroll
        for (int cf = 0; cf < 8; ++cf)
            acc[cf] = __builtin_amdgcn_mfma_f32_16x16x32_bf16(av, bv[cf], acc[cf], 0, 0, 0);
    }

    // fused a_src/a_dst: reduce over cols within each head
    float att_s[8], att_d[8];
#pragma unroll
    for (int cf = 0; cf < 8; ++cf) {
        att_s[cf] = att_src[cf * 16 + lr];
        att_d[cf] = att_dst[cf * 16 + lr];
    }
#pragma unroll
    for (int reg = 0; reg < 4; ++reg) {
        int row = row0 + w * 16 + lg * 4 + reg;
        float ps[4], pd[4];
#pragma unroll
        for (int hh = 0; hh < 4; ++hh) {
            ps[hh] = acc[2 * hh][reg] * att_s[2 * hh] + acc[2 * hh + 1][reg] * att_s[2 * hh + 1];
            pd[hh] = acc[2 * hh][reg] * att_d[2 * hh] + acc[2 * hh + 1][reg] * att_d[2 * hh + 1];
        }
#pragma unroll
        for (int m = 1; m <= 8; m <<= 1) {
#pragma unroll
            for (int hh = 0; hh < 4; ++hh) {
                ps[hh] += __shfl_xor(ps[hh], m);
                pd[hh] += __shfl_xor(pd[hh], m);
            }
        }
        if (lr == 0 && row < N) {
            ((float4*)a_src)[row] = float4{ps[0], ps[1], ps[2], ps[3]};
            ((float4*)a_dst)[row] = float4{pd[0], pd[1], pd[2], pd[3]};
        }
    }

    // hb via per-wave-private LDS scratch (this wave's own smA rows), then
    // fully-coalesced uint4 stores.
    unsigned char* scratch = smA + (size_t)w * 4096;  // 16 rows x 256B
#pragma unroll
    for (int cf = 0; cf < 8; ++cf) {
#pragma unroll
        for (int reg = 0; reg < 4; ++reg) {
            float v = acc[cf][reg];
            float vo = __shfl_xor(v, 1);
            if (!(lane & 1))
                *(unsigned*)&scratch[(lg * 4 + reg) * 256 + cf * 32 + (lr >> 1) * 4] =
                    bf16pair(v, vo);
        }
    }
#pragma unroll
    for (int q = 0; q < 4; ++q) {
        uint4 u = *(const uint4*)&scratch[q * 1024 + lane * 16];
        int row = row0 + w * 16 + q * 4 + lg;
        if (row < N) ((uint4*)hb)[(size_t)row * 16 + lr] = u;
    }
}

// ---------------- exclusive scan (2 kernels; apply fused downstream) ---------
__global__ void k_scan1(const unsigned* __restrict__ deg, unsigned* __restrict__ part,
                        unsigned* __restrict__ blockSums, int N) {
    __shared__ unsigned s[256];
    int t = threadIdx.x;
    int i = blockIdx.x * 256 + t;
    unsigned v = (i < N) ? deg[i] : 0u;
    s[t] = v;
    __syncthreads();
    for (int off = 1; off < 256; off <<= 1) {
        unsigned a = (t >= off) ? s[t - off] : 0u;
        __syncthreads();
        s[t] += a;
        __syncthreads();
    }
    if (i < N) part[i] = s[t] - v;
    if (t == 255) blockSums[blockIdx.x] = s[255];
}

__global__ void k_scan2(const unsigned* __restrict__ blockSums,
                        unsigned* __restrict__ blockScan, int NB) {
    __shared__ unsigned s[512];
    int t = threadIdx.x;
    unsigned v = (t < NB) ? blockSums[t] : 0u;
    s[t] = v;
    __syncthreads();
    for (int off = 1; off < 512; off <<= 1) {
        unsigned a = (t >= off) ? s[t - off] : 0u;
        __syncthreads();
        s[t] += a;
        __syncthreads();
    }
    if (t < NB) blockScan[t] = s[t] - v;
}

// ---------------- scatter: build 16B CSR entries {src, p01_f16, p23_f16, 0} --
__global__ void k_scatter(const int* __restrict__ ei, int E,
                          const float* __restrict__ a_src, const float* __restrict__ a_dst,
                          const unsigned* __restrict__ part,
                          const unsigned* __restrict__ blockScan,
                          unsigned* __restrict__ cursor, uint4* __restrict__ csr) {
    int e = blockIdx.x * 256 + threadIdx.x;
    if (e >= E) return;
    int s = ei[e];
    int d = ei[(size_t)E + e];
    float4 as = ((const float4*)a_src)[s];
    float4 ad = ((const float4*)a_dst)[d];
    float p0 = __expf(lrelu(as.x + ad.x));
    float p1 = __expf(lrelu(as.y + ad.y));
    float p2 = __expf(lrelu(as.z + ad.z));
    float p3 = __expf(lrelu(as.w + ad.w));
    unsigned p01 = __builtin_bit_cast(unsigned, __builtin_amdgcn_cvt_pkrtz(p0, p1));
    unsigned p23 = __builtin_bit_cast(unsigned, __builtin_amdgcn_cvt_pkrtz(p2, p3));
    unsigned pos = part[d] + blockScan[d >> 8] + atomicAdd(&cursor[d], 1u);
    csr[pos] = uint4{(unsigned)s, p01, p23, 0u};
}

// ---------------- gather: one wave per dst node, clamped 8-wide MLP ----------
__global__ __launch_bounds__(256) void k_gather(const unsigned* __restrict__ hb,
                                                const uint4* __restrict__ csr,
                                                const unsigned* __restrict__ part,
                                                const unsigned* __restrict__ blockScan,
                                                const unsigned* __restrict__ deg,
                                                const float* __restrict__ a_src,
                                                const float* __restrict__ a_dst,
                                                const float* __restrict__ bias,
                                                float* __restrict__ out, int N) {
    int n = (int)((blockIdx.x * 256 + threadIdx.x) >> 6);
    int lane = threadIdx.x & 63;
    if (n >= N) return;
    int head = lane >> 4;
    unsigned off = part[n] + blockScan[n >> 8];
    unsigned end = off + deg[n];
    float ax = 0.f, ay = 0.f, dsum = 0.f;
    for (unsigned b = off; b < end; b += 8) {
        uint4 Ee[8];
#pragma unroll
        for (int i = 0; i < 8; ++i) {
            unsigned idx = b + i;
            if (idx >= end) idx = end - 1;
            Ee[i] = csr[idx];
        }
#pragma unroll
        for (int i = 0; i < 8; ++i) {
            unsigned pw = (head & 2) ? Ee[i].z : Ee[i].y;
            unsigned hv = (head & 1) ? (pw >> 16) : (pw & 0xFFFFu);
            float p = (float)__builtin_bit_cast(_Float16, (unsigned short)hv);
            p = (b + i < end) ? p : 0.f;
            unsigned u = hb[(size_t)Ee[i].x * 64 + lane];
            ax = fmaf(p, __uint_as_float(u << 16), ax);
            ay = fmaf(p, __uint_as_float(u & 0xFFFF0000u), ay);
            dsum += p;
        }
    }
    // self loop (fp32 p)
    float p_self = __expf(lrelu(a_src[n * 4 + head] + a_dst[n * 4 + head]));
    unsigned us = hb[(size_t)n * 64 + lane];
    ax = fmaf(p_self, __uint_as_float(us << 16), ax);
    ay = fmaf(p_self, __uint_as_float(us & 0xFFFF0000u), ay);
    dsum += p_self;
    float inv = 1.0f / dsum;
    float2 b2 = ((const float2*)bias)[lane];
    float ox = ax * inv + b2.x;
    float oy = ay * inv + b2.y;
    ox = ox > 0.f ? ox : (__expf(ox) - 1.0f);
    oy = oy > 0.f ? oy : (__expf(oy) - 1.0f);
    ((float2*)out)[(size_t)n * 64 + lane] = float2{ox, oy};
}

extern "C" void kernel_launch(void* const* d_in, const int* in_sizes, int n_in,
                              void* d_out, int out_size, void* d_ws, size_t ws_size,
                              hipStream_t stream) {
    const float* x = (const float*)d_in[0];
    const int* ei = (const int*)d_in[1];
    const float* W = (const float*)d_in[2];
    const float* att_src = (const float*)d_in[3];
    const float* att_dst = (const float*)d_in[4];
    const float* bias = (const float*)d_in[5];
    int N = in_sizes[0] / 128;
    int E = in_sizes[1] / 2;

    char* ws = (char*)d_ws;
    size_t o = 0;
    unsigned* hb = (unsigned*)(ws + o);   o += (size_t)N * 64 * 4;   // 25.6 MB bf16 h
    float* a_src = (float*)(ws + o);      o += (size_t)N * 4 * 4;
    float* a_dst = (float*)(ws + o);      o += (size_t)N * 4 * 4;
    uint4* csr = (uint4*)(ws + o);        o += (size_t)E * 16;       // 25.6 MB
    unsigned short* Wt = (unsigned short*)(ws + o); o += 128 * 128 * 2;
    unsigned* deg = (unsigned*)(ws + o);  o += (size_t)N * 4;
    unsigned* cur = (unsigned*)(ws + o);  o += (size_t)N * 4;        // adjacent to deg
    unsigned* part = (unsigned*)(ws + o); o += (size_t)N * 4;
    unsigned* blockSums = (unsigned*)(ws + o); o += 2048;
    unsigned* blockScan = (unsigned*)(ws + o); o += 2048;

    // xb (bf16 x) lives in d_out scratch: only read by k_gemm, and d_out is
    // fully rewritten by k_gather at the end.
    unsigned* xb = (unsigned*)d_out;

    hipMemsetAsync(deg, 0, (size_t)N * 8, stream);  // deg + cur

    k_prep<<<2048, 256, 0, stream>>>(x, W, ei, deg, xb, Wt, N, E);
    k_gemm<<<(N + 127) / 128, 512, 0, stream>>>(xb, Wt, att_src, att_dst, hb, a_src, a_dst, N);
    int NB = (N + 255) / 256;
    k_scan1<<<NB, 256, 0, stream>>>(deg, part, blockSums, N);
    k_scan2<<<1, 512, 0, stream>>>(blockSums, blockScan, NB);
    k_scatter<<<(E + 255) / 256, 256, 0, stream>>>(ei, E, a_src, a_dst, part, blockScan, cur, csr);
    k_gather<<<(N * 64 + 255) / 256, 256, 0, stream>>>(hb, csr, part, blockScan, deg, a_src,
                                                       a_dst, bias, (float*)d_out, N);
}